// Round 1
// baseline (1344.096 us; speedup 1.0000x reference)
//
#include <hip/hip_runtime.h>
#include <stdint.h>

using u16 = unsigned short;
typedef __attribute__((ext_vector_type(8))) __bf16 bf16x8;
typedef __attribute__((ext_vector_type(4))) float f32x4;

#define DEV __device__ __forceinline__

static constexpr int kB = 4, kL = 4096, kD = 1024, kFF = 4096;
static constexpr int kM = kB * kL;          // 16384 tokens
static constexpr int kLC = 64, kNC = kL / kLC;  // scan chunking
static constexpr float kEPS = 1e-6f;

DEV u16 f2bf(float v) {
  union { float f; uint32_t u; } x; x.f = v;
  uint32_t r = x.u + 0x7FFFu + ((x.u >> 16) & 1u);  // RNE
  return (u16)(r >> 16);
}
DEV float sigm(float x) { return 1.0f / (1.0f + __expf(-x)); }

DEV void gload_lds16(const void* g, void* l) {
  __builtin_amdgcn_global_load_lds(
      (const __attribute__((address_space(1))) void*)g,
      (__attribute__((address_space(3))) void*)l, 16, 0, 0);
}

// ---------------- weight transpose + f32->bf16: out[n*K+k] = bf16(in[k*N+n])
__global__ __launch_bounds__(256) void wtrans_kernel(const float* __restrict__ in,
                                                     u16* __restrict__ out,
                                                     int K, int N) {
  __shared__ float t[32][33];
  const int n0 = blockIdx.x * 32, k0 = blockIdx.y * 32;
  const int tx = threadIdx.x, ty = threadIdx.y;
#pragma unroll
  for (int i = 0; i < 4; ++i)
    t[ty + i * 8][tx] = in[(size_t)(k0 + ty + i * 8) * N + (n0 + tx)];
  __syncthreads();
#pragma unroll
  for (int i = 0; i < 4; ++i)
    out[(size_t)(n0 + ty + i * 8) * K + (k0 + tx)] = f2bf(t[tx][ty + i * 8]);
}

// ---------------- RMSNorm (f32 in, bf16 out), one block per row, D=1024
__global__ __launch_bounds__(256) void rmsnorm_kernel(const float* __restrict__ x,
                                                      const float* __restrict__ g,
                                                      u16* __restrict__ out) {
  const int row = blockIdx.x;
  const int t = threadIdx.x;
  const float4 v = ((const float4*)(x + (size_t)row * kD))[t];
  float ss = v.x * v.x + v.y * v.y + v.z * v.z + v.w * v.w;
#pragma unroll
  for (int o = 1; o < 64; o <<= 1) ss += __shfl_xor(ss, o, 64);
  __shared__ float red[4];
  if ((t & 63) == 0) red[t >> 6] = ss;
  __syncthreads();
  const float tot = red[0] + red[1] + red[2] + red[3];
  const float sc = rsqrtf(tot * (1.0f / kD) + kEPS);
  const float4 gv = ((const float4*)g)[t];
  const uint32_t lo = (uint32_t)f2bf(v.x * sc * gv.x) | ((uint32_t)f2bf(v.y * sc * gv.y) << 16);
  const uint32_t hi = (uint32_t)f2bf(v.z * sc * gv.z) | ((uint32_t)f2bf(v.w * sc * gv.w) << 16);
  *(uint2*)(out + (size_t)row * kD + t * 4) = make_uint2(lo, hi);
}

// ---------------- GEMM: C = act(A[M,K] @ Bt[N,K]^T + bias), bf16 in, fused epilogues.
// MODE 0: Cf = v
// MODE 1: Cf = sigmoid(-v); C2 = sigmoid(aux)*sigmoid(v)      (scan coeffs A,B)
// MODE 2: Cf = v*silu(aux) + res                               (y + residual)
// MODE 3: Cb = bf16(v*silu(aux))                               (FFN gate -> U)
// MODE 4: Cf = v + res                                         (final out)
template <int MODE>
__global__ __launch_bounds__(256) void gemm_bt(
    const u16* __restrict__ A, const u16* __restrict__ Bt,
    const float* __restrict__ bias, const float* __restrict__ aux,
    const float* __restrict__ res, float* __restrict__ Cf,
    u16* __restrict__ Cb, float* __restrict__ C2,
    int M, int N, int K) {
  __shared__ u16 As[128 * 32];
  __shared__ u16 Bs[128 * 32];
  const int tid = threadIdx.x;
  const int lane = tid & 63;
  const int wave = tid >> 6;
  const int wr = wave >> 1, wc = wave & 1;
  const int m0 = blockIdx.y * 128, n0 = blockIdx.x * 128;
  const int lr = tid >> 2;          // staging row within 64-row half
  const int lc = (tid & 3) * 8;     // staging k-offset (elements)
  f32x4 acc[4][4] = {};
  const size_t rowA0 = (size_t)(m0 + lr) * K;
  const size_t rowA1 = (size_t)(m0 + 64 + lr) * K;
  const size_t rowB0 = (size_t)(n0 + lr) * K;
  const size_t rowB1 = (size_t)(n0 + 64 + lr) * K;
  for (int k0 = 0; k0 < K; k0 += 32) {
    __syncthreads();
    gload_lds16(A + rowA0 + k0 + lc, As + tid * 8);
    gload_lds16(A + rowA1 + k0 + lc, As + 2048 + tid * 8);
    gload_lds16(Bt + rowB0 + k0 + lc, Bs + tid * 8);
    gload_lds16(Bt + rowB1 + k0 + lc, Bs + 2048 + tid * 8);
    __syncthreads();
    const int kq = (lane >> 4) * 8;
    const int ra = lane & 15;
    bf16x8 af[4], bfr[4];
#pragma unroll
    for (int mi = 0; mi < 4; ++mi)
      af[mi] = *(const bf16x8*)(As + (wr * 64 + mi * 16 + ra) * 32 + kq);
#pragma unroll
    for (int ni = 0; ni < 4; ++ni)
      bfr[ni] = *(const bf16x8*)(Bs + (wc * 64 + ni * 16 + ra) * 32 + kq);
#pragma unroll
    for (int mi = 0; mi < 4; ++mi)
#pragma unroll
      for (int ni = 0; ni < 4; ++ni)
        acc[mi][ni] = __builtin_amdgcn_mfma_f32_16x16x32_bf16(af[mi], bfr[ni], acc[mi][ni], 0, 0, 0);
  }
  // C/D layout (HW-verified): col = lane&15, row = (lane>>4)*4 + j
  const int ca = lane & 15;
  const int rq = (lane >> 4) * 4;
#pragma unroll
  for (int mi = 0; mi < 4; ++mi) {
#pragma unroll
    for (int ni = 0; ni < 4; ++ni) {
      const int c = n0 + wc * 64 + ni * 16 + ca;
      const float bz = bias[c];
#pragma unroll
      for (int j = 0; j < 4; ++j) {
        const int r = m0 + wr * 64 + mi * 16 + rq + j;
        const size_t idx = (size_t)r * N + c;
        const float v = acc[mi][ni][j] + bz;
        if (MODE == 0) {
          Cf[idx] = v;
        } else if (MODE == 1) {
          Cf[idx] = sigm(-v);                       // decay A
          C2[idx] = sigm(aux[idx]) * sigm(v);       // input B
        } else if (MODE == 2) {
          const float a = aux[idx];
          Cf[idx] = v * (a * sigm(a)) + res[idx];
        } else if (MODE == 3) {
          const float a = aux[idx];
          Cb[idx] = f2bf(v * (a * sigm(a)));
        } else {
          Cf[idx] = v + res[idx];
        }
      }
    }
  }
}

// ---------------- chunked scan: h[l] = A[l]*h[l-1] + B[l]
__global__ __launch_bounds__(256) void scan_phase1(const float* __restrict__ Aa,
                                                   const float* __restrict__ Bv,
                                                   float* __restrict__ P,
                                                   float* __restrict__ S) {
  const int d = blockIdx.x * 256 + threadIdx.x;
  const int c = blockIdx.y, b = blockIdx.z;
  size_t base = ((size_t)b * kL + (size_t)c * kLC) * kD + d;
  float p = 1.0f, s = 0.0f;
#pragma unroll 4
  for (int l = 0; l < kLC; ++l) {
    const float a = Aa[base];
    const float bv = Bv[base];
    p *= a;
    s = fmaf(a, s, bv);
    base += kD;
  }
  const size_t o = ((size_t)b * kNC + c) * kD + d;
  P[o] = p; S[o] = s;
}

__global__ __launch_bounds__(256) void scan_phase2(const float* __restrict__ P,
                                                   const float* __restrict__ S,
                                                   const float* __restrict__ hidden,
                                                   float* __restrict__ Hini) {
  const int d = blockIdx.x * 256 + threadIdx.x;
  const int b = blockIdx.y;
  float carry = hidden[(size_t)b * kD + d];
  for (int c = 0; c < kNC; ++c) {
    const size_t o = ((size_t)b * kNC + c) * kD + d;
    Hini[o] = carry;
    carry = fmaf(P[o], carry, S[o]);
  }
}

__global__ __launch_bounds__(256) void scan_phase3(const float* __restrict__ Aa,
                                                   const float* __restrict__ Bv,
                                                   const float* __restrict__ Hini,
                                                   float* __restrict__ Hout,
                                                   u16* __restrict__ Hbf) {
  const int d = blockIdx.x * 256 + threadIdx.x;
  const int c = blockIdx.y, b = blockIdx.z;
  float h = Hini[((size_t)b * kNC + c) * kD + d];
  size_t base = ((size_t)b * kL + (size_t)c * kLC) * kD + d;
#pragma unroll 4
  for (int l = 0; l < kLC; ++l) {
    h = fmaf(Aa[base], h, Bv[base]);
    Hout[base] = h;
    Hbf[base] = f2bf(h);
    base += kD;
  }
}

// ---------------- host
extern "C" void kernel_launch(void* const* d_in, const int* in_sizes, int n_in,
                              void* d_out, int out_size, void* d_ws, size_t ws_size,
                              hipStream_t stream) {
  const float* x      = (const float*)d_in[0];
  const float* hidden = (const float*)d_in[1];
  const float* w_ln_z = (const float*)d_in[2];
  const float* b_ln_z = (const float*)d_in[3];
  const float* w_dt   = (const float*)d_in[4];
  const float* b_dt   = (const float*)d_in[5];
  const float* w_y    = (const float*)d_in[6];
  const float* b_y    = (const float*)d_in[7];
  const float* w_yact = (const float*)d_in[8];
  const float* b_yact = (const float*)d_in[9];
  const float* w_fc   = (const float*)d_in[10];
  const float* b_fc   = (const float*)d_in[11];
  const float* w_fca  = (const float*)d_in[12];
  const float* b_fca  = (const float*)d_in[13];
  const float* w_out  = (const float*)d_in[14];
  const float* b_out  = (const float*)d_in[15];
  const float* g_sio  = (const float*)d_in[16];
  const float* g_ffn  = (const float*)d_in[17];

  char* ws = (char*)d_ws;
  const size_t MiB = 1ull << 20;
  u16* wlnzT = (u16*)(ws + 0 * MiB);    // 2 MiB each for DxD
  u16* wdtT  = (u16*)(ws + 2 * MiB);
  u16* wyT   = (u16*)(ws + 4 * MiB);
  u16* wyaT  = (u16*)(ws + 6 * MiB);
  u16* wfcT  = (u16*)(ws + 8 * MiB);    // [FF,D] bf16 = 8 MiB
  u16* wfcaT = (u16*)(ws + 16 * MiB);
  u16* woutT = (u16*)(ws + 24 * MiB);   // [D,FF] bf16 = 8 MiB
  u16*   xn    = (u16*)(ws + 32 * MiB);   // [M,D] bf16 (also xn2 later)
  float* zbuf  = (float*)(ws + 64 * MiB); // [M,D] f32 (z, later YA)
  float* Abuf  = (float*)(ws + 128 * MiB);// [M,D] f32 (later Ga chunk)
  float* Bvbuf = (float*)(ws + 192 * MiB);// [M,D] f32 (later U chunk bf16)
  u16*   hbf   = (u16*)(ws + 256 * MiB);  // [M,D] bf16
  float* Pbuf  = (float*)(ws + 288 * MiB);// [B,NC,D]
  float* Sbuf  = (float*)(ws + 289 * MiB);
  float* Hini  = (float*)(ws + 290 * MiB);
  float* x1    = (float*)(ws + 291 * MiB);// [M,D] f32, ends at 355 MiB

  float* xout = (float*)d_out;
  float* hout = xout + (size_t)kM * kD;

  const dim3 tb(32, 8);
  wtrans_kernel<<<dim3(kD / 32, kD / 32), tb, 0, stream>>>(w_ln_z, wlnzT, kD, kD);
  wtrans_kernel<<<dim3(kD / 32, kD / 32), tb, 0, stream>>>(w_dt, wdtT, kD, kD);
  wtrans_kernel<<<dim3(kD / 32, kD / 32), tb, 0, stream>>>(w_y, wyT, kD, kD);
  wtrans_kernel<<<dim3(kD / 32, kD / 32), tb, 0, stream>>>(w_yact, wyaT, kD, kD);
  wtrans_kernel<<<dim3(kFF / 32, kD / 32), tb, 0, stream>>>(w_fc, wfcT, kD, kFF);
  wtrans_kernel<<<dim3(kFF / 32, kD / 32), tb, 0, stream>>>(w_fca, wfcaT, kD, kFF);
  wtrans_kernel<<<dim3(kD / 32, kFF / 32), tb, 0, stream>>>(w_out, woutT, kFF, kD);

  rmsnorm_kernel<<<kM, 256, 0, stream>>>(x, g_sio, xn);

  // z = xn @ w_ln_z + b
  gemm_bt<0><<<dim3(kD / 128, kM / 128), 256, 0, stream>>>(
      xn, wlnzT, b_ln_z, nullptr, nullptr, zbuf, nullptr, nullptr, kM, kD, kD);
  // dt GEMM -> scan coeffs A=sigmoid(-dt), B=sigmoid(z)*sigmoid(dt)
  gemm_bt<1><<<dim3(kD / 128, kM / 128), 256, 0, stream>>>(
      xn, wdtT, b_dt, zbuf, nullptr, Abuf, nullptr, Bvbuf, kM, kD, kD);
  // ya = xn @ w_y_act + b  (reuses zbuf)
  gemm_bt<0><<<dim3(kD / 128, kM / 128), 256, 0, stream>>>(
      xn, wyaT, b_yact, nullptr, nullptr, zbuf, nullptr, nullptr, kM, kD, kD);

  scan_phase1<<<dim3(kD / 256, kNC, kB), 256, 0, stream>>>(Abuf, Bvbuf, Pbuf, Sbuf);
  scan_phase2<<<dim3(kD / 256, kB), 256, 0, stream>>>(Pbuf, Sbuf, hidden, Hini);
  scan_phase3<<<dim3(kD / 256, kNC, kB), 256, 0, stream>>>(Abuf, Bvbuf, Hini, hout, hbf);

  // x1 = (h @ w_y + b_y) * silu(ya) + x
  gemm_bt<2><<<dim3(kD / 128, kM / 128), 256, 0, stream>>>(
      hbf, wyT, b_y, zbuf, x, x1, nullptr, nullptr, kM, kD, kD);

  rmsnorm_kernel<<<kM, 256, 0, stream>>>(x1, g_ffn, xn);  // xn2 reuses xn

  // FFN in 4 M-chunks to bound workspace
  float* Ga = Abuf;
  u16* Ubuf = (u16*)Bvbuf;
  for (int ci = 0; ci < 4; ++ci) {
    const u16* xc = xn + (size_t)ci * 4096 * kD;
    const float* resc = x1 + (size_t)ci * 4096 * kD;
    float* outc = xout + (size_t)ci * 4096 * kD;
    gemm_bt<0><<<dim3(kFF / 128, 4096 / 128), 256, 0, stream>>>(
        xc, wfcaT, b_fca, nullptr, nullptr, Ga, nullptr, nullptr, 4096, kFF, kD);
    gemm_bt<3><<<dim3(kFF / 128, 4096 / 128), 256, 0, stream>>>(
        xc, wfcT, b_fc, Ga, nullptr, nullptr, Ubuf, nullptr, 4096, kFF, kD);
    gemm_bt<4><<<dim3(kD / 128, 4096 / 128), 256, 0, stream>>>(
        Ubuf, woutT, b_out, nullptr, resc, outc, nullptr, nullptr, 4096, kD, kFF);
  }
}

// Round 2
// 1015.385 us; speedup vs baseline: 1.3237x; 1.3237x over previous
//
#include <hip/hip_runtime.h>
#include <stdint.h>

using u16 = unsigned short;
typedef __attribute__((ext_vector_type(8))) __bf16 bf16x8;
typedef __attribute__((ext_vector_type(4))) float f32x4;

#define DEV __device__ __forceinline__

static constexpr int kB = 4, kL = 4096, kD = 1024, kFF = 4096;
static constexpr int kM = kB * kL;
static constexpr int kLC = 64, kNC = kL / kLC;
static constexpr float kEPS = 1e-6f;

DEV u16 f2bf(float v) {
  union { float f; uint32_t u; } x; x.f = v;
  uint32_t r = x.u + 0x7FFFu + ((x.u >> 16) & 1u);  // RNE
  return (u16)(r >> 16);
}
DEV float bf2f(u16 u) {
  union { uint32_t u; float f; } x; x.u = (uint32_t)u << 16; return x.f;
}
DEV float sigm(float x) { return 1.0f / (1.0f + __expf(-x)); }

DEV void gload_lds16(const void* g, void* l) {
  __builtin_amdgcn_global_load_lds(
      (const __attribute__((address_space(1))) void*)g,
      (__attribute__((address_space(3))) void*)l, 16, 0, 0);
}

// ---------------- weight transpose + f32->bf16: out[n*K+k] = bf16(in[k*N+n])
__global__ __launch_bounds__(256) void wtrans_kernel(const float* __restrict__ in,
                                                     u16* __restrict__ out,
                                                     int K, int N) {
  __shared__ float t[32][33];
  const int n0 = blockIdx.x * 32, k0 = blockIdx.y * 32;
  const int tx = threadIdx.x, ty = threadIdx.y;
#pragma unroll
  for (int i = 0; i < 4; ++i)
    t[ty + i * 8][tx] = in[(size_t)(k0 + ty + i * 8) * N + (n0 + tx)];
  __syncthreads();
#pragma unroll
  for (int i = 0; i < 4; ++i)
    out[(size_t)(n0 + ty + i * 8) * K + (k0 + tx)] = f2bf(t[tx][ty + i * 8]);
}

__global__ __launch_bounds__(256) void concat_bias(const float* __restrict__ a,
                                                   const float* __restrict__ b,
                                                   float* __restrict__ o) {
  const int i = blockIdx.x * 256 + threadIdx.x;
  if (i < 1024) o[i] = a[i];
  else if (i < 2048) o[i] = b[i - 1024];
}

// ---------------- RMSNorm (f32 in, bf16 out), one block per row, D=1024
__global__ __launch_bounds__(256) void rmsnorm_kernel(const float* __restrict__ x,
                                                      const float* __restrict__ g,
                                                      u16* __restrict__ out) {
  const int row = blockIdx.x;
  const int t = threadIdx.x;
  const float4 v = ((const float4*)(x + (size_t)row * kD))[t];
  float ss = v.x * v.x + v.y * v.y + v.z * v.z + v.w * v.w;
#pragma unroll
  for (int o = 1; o < 64; o <<= 1) ss += __shfl_xor(ss, o, 64);
  __shared__ float red[4];
  if ((t & 63) == 0) red[t >> 6] = ss;
  __syncthreads();
  const float tot = red[0] + red[1] + red[2] + red[3];
  const float sc = rsqrtf(tot * (1.0f / kD) + kEPS);
  const float4 gv = ((const float4*)g)[t];
  const uint32_t lo = (uint32_t)f2bf(v.x * sc * gv.x) | ((uint32_t)f2bf(v.y * sc * gv.y) << 16);
  const uint32_t hi = (uint32_t)f2bf(v.z * sc * gv.z) | ((uint32_t)f2bf(v.w * sc * gv.w) << 16);
  *(uint2*)(out + (size_t)row * kD + t * 4) = make_uint2(lo, hi);
}

// ---------------- GEMM: C = epilogue(A[M,K] @ Bt[N,K]^T + bias)
// 2-phase double-buffered staging; bijective XCD swizzle.
// MODE 1: Cf = sigmoid(-v); C2 = sigmoid(aux)*sigmoid(v)   (scan coeffs A,B; aux=z bf16)
// MODE 2: Cf = v*silu(aux) + res                            (y + residual; aux=ya bf16)
// MODE 3: Cb = bf16(v*silu(aux))                            (FFN gate -> U; aux=Ga bf16)
// MODE 4: Cf = v + res                                      (final out)
// MODE 5: Cb = bf16(v)                                      (raw bf16 store)
template <int MODE>
__global__ __launch_bounds__(256) void gemm_bt(
    const u16* __restrict__ A, const u16* __restrict__ Bt,
    const float* __restrict__ bias, const u16* __restrict__ aux, int auxld,
    const float* __restrict__ res, float* __restrict__ Cf,
    u16* __restrict__ Cb, float* __restrict__ C2,
    int M, int N, int K) {
  __shared__ u16 As[2][4096];   // [buf][128 rows x 32 k]
  __shared__ u16 Bs[2][4096];
  const int tid = threadIdx.x;
  const int lane = tid & 63;
  const int wave = tid >> 6;
  const int wr = wave >> 1, wc = wave & 1;

  // bijective XCD-aware block swizzle (m204)
  const int gx = gridDim.x;
  const int nwg = gx * gridDim.y;
  const int bid = blockIdx.y * gx + blockIdx.x;
  const int q = nwg >> 3, r = nwg & 7;
  const int xcd = bid & 7, idx0 = bid >> 3;
  const int wg = (xcd < r ? xcd * (q + 1) : r * (q + 1) + (xcd - r) * q) + idx0;
  const int m0 = (wg / gx) * 128, n0 = (wg % gx) * 128;

  const int lr = tid >> 2;          // staging row within 64-row half
  const int lc = (tid & 3) * 8;     // staging k-offset (elements)
  f32x4 acc[4][4] = {};
  const size_t rowA0 = (size_t)(m0 + lr) * K + lc;
  const size_t rowA1 = (size_t)(m0 + 64 + lr) * K + lc;
  const size_t rowB0 = (size_t)(n0 + lr) * K + lc;
  const size_t rowB1 = (size_t)(n0 + 64 + lr) * K + lc;

  auto stage = [&](int k0, int b) {
    gload_lds16(A + rowA0 + k0, &As[b][tid * 8]);
    gload_lds16(A + rowA1 + k0, &As[b][2048 + tid * 8]);
    gload_lds16(Bt + rowB0 + k0, &Bs[b][tid * 8]);
    gload_lds16(Bt + rowB1 + k0, &Bs[b][2048 + tid * 8]);
  };

  stage(0, 0);
  __syncthreads();                  // drains vmcnt: buf0 ready
  int cur = 0;
  const int kq = (lane >> 4) * 8;
  const int ra = lane & 15;
  for (int k0 = 0; k0 < K; k0 += 32) {
    if (k0 + 32 < K) stage(k0 + 32, cur ^ 1);   // prefetch next tile (in flight over MFMA)
    const u16* as = As[cur];
    const u16* bs = Bs[cur];
    bf16x8 af[4], bfr[4];
#pragma unroll
    for (int mi = 0; mi < 4; ++mi)
      af[mi] = *(const bf16x8*)(as + (wr * 64 + mi * 16 + ra) * 32 + kq);
#pragma unroll
    for (int ni = 0; ni < 4; ++ni)
      bfr[ni] = *(const bf16x8*)(bs + (wc * 64 + ni * 16 + ra) * 32 + kq);
#pragma unroll
    for (int mi = 0; mi < 4; ++mi)
#pragma unroll
      for (int ni = 0; ni < 4; ++ni)
        acc[mi][ni] = __builtin_amdgcn_mfma_f32_16x16x32_bf16(af[mi], bfr[ni], acc[mi][ni], 0, 0, 0);
    __syncthreads();                // drains vmcnt (next buf staged) + guards reuse
    cur ^= 1;
  }

  // C/D layout (HW-verified): col = lane&15, row = (lane>>4)*4 + j
  const int ca = lane & 15;
  const int rq = (lane >> 4) * 4;
#pragma unroll
  for (int mi = 0; mi < 4; ++mi) {
#pragma unroll
    for (int ni = 0; ni < 4; ++ni) {
      const int c = n0 + wc * 64 + ni * 16 + ca;
      const float bz = bias[c];
#pragma unroll
      for (int j = 0; j < 4; ++j) {
        const int rr = m0 + wr * 64 + mi * 16 + rq + j;
        const size_t idx = (size_t)rr * N + c;
        const float v = acc[mi][ni][j] + bz;
        if (MODE == 1) {
          Cf[idx] = sigm(-v);
          C2[idx] = sigm(bf2f(aux[(size_t)rr * auxld + c])) * sigm(v);
        } else if (MODE == 2) {
          const float a = bf2f(aux[(size_t)rr * auxld + c]);
          Cf[idx] = v * (a * sigm(a)) + res[idx];
        } else if (MODE == 3) {
          const float a = bf2f(aux[(size_t)rr * auxld + c]);
          Cb[idx] = f2bf(v * (a * sigm(a)));
        } else if (MODE == 4) {
          Cf[idx] = v + res[idx];
        } else {  // MODE 5
          Cb[idx] = f2bf(v);
        }
      }
    }
  }
}

// ---------------- chunked scan: h[l] = A[l]*h[l-1] + B[l]
__global__ __launch_bounds__(256) void scan_phase1(const float* __restrict__ Aa,
                                                   const float* __restrict__ Bv,
                                                   float* __restrict__ P,
                                                   float* __restrict__ S) {
  const int d = blockIdx.x * 256 + threadIdx.x;
  const int c = blockIdx.y, b = blockIdx.z;
  size_t base = ((size_t)b * kL + (size_t)c * kLC) * kD + d;
  float p = 1.0f, s = 0.0f;
#pragma unroll 4
  for (int l = 0; l < kLC; ++l) {
    const float a = Aa[base];
    const float bv = Bv[base];
    p *= a;
    s = fmaf(a, s, bv);
    base += kD;
  }
  const size_t o = ((size_t)b * kNC + c) * kD + d;
  P[o] = p; S[o] = s;
}

__global__ __launch_bounds__(256) void scan_phase2(const float* __restrict__ P,
                                                   const float* __restrict__ S,
                                                   const float* __restrict__ hidden,
                                                   float* __restrict__ Hini) {
  const int d = blockIdx.x * 256 + threadIdx.x;
  const int b = blockIdx.y;
  float carry = hidden[(size_t)b * kD + d];
  for (int c = 0; c < kNC; ++c) {
    const size_t o = ((size_t)b * kNC + c) * kD + d;
    Hini[o] = carry;
    carry = fmaf(P[o], carry, S[o]);
  }
}

__global__ __launch_bounds__(256) void scan_phase3(const float* __restrict__ Aa,
                                                   const float* __restrict__ Bv,
                                                   const float* __restrict__ Hini,
                                                   float* __restrict__ Hout,
                                                   u16* __restrict__ Hbf) {
  const int d = blockIdx.x * 256 + threadIdx.x;
  const int c = blockIdx.y, b = blockIdx.z;
  float h = Hini[((size_t)b * kNC + c) * kD + d];
  size_t base = ((size_t)b * kL + (size_t)c * kLC) * kD + d;
#pragma unroll 4
  for (int l = 0; l < kLC; ++l) {
    h = fmaf(Aa[base], h, Bv[base]);
    Hout[base] = h;
    Hbf[base] = f2bf(h);
    base += kD;
  }
}

// ---------------- host
extern "C" void kernel_launch(void* const* d_in, const int* in_sizes, int n_in,
                              void* d_out, int out_size, void* d_ws, size_t ws_size,
                              hipStream_t stream) {
  const float* x      = (const float*)d_in[0];
  const float* hidden = (const float*)d_in[1];
  const float* w_ln_z = (const float*)d_in[2];
  const float* b_ln_z = (const float*)d_in[3];
  const float* w_dt   = (const float*)d_in[4];
  const float* b_dt   = (const float*)d_in[5];
  const float* w_y    = (const float*)d_in[6];
  const float* b_y    = (const float*)d_in[7];
  const float* w_yact = (const float*)d_in[8];
  const float* b_yact = (const float*)d_in[9];
  const float* w_fc   = (const float*)d_in[10];
  const float* b_fc   = (const float*)d_in[11];
  const float* w_fca  = (const float*)d_in[12];
  const float* b_fca  = (const float*)d_in[13];
  const float* w_out  = (const float*)d_in[14];
  const float* b_out  = (const float*)d_in[15];
  const float* g_sio  = (const float*)d_in[16];
  const float* g_ffn  = (const float*)d_in[17];

  char* ws = (char*)d_ws;
  const size_t MiB = 1ull << 20;
  u16* wzyaT = (u16*)(ws + 0 * MiB);      // [2048,1024] bf16 = 4 MiB (ln_z | y_act)
  u16* wdtT  = (u16*)(ws + 4 * MiB);      // 2 MiB
  u16* wyT   = (u16*)(ws + 6 * MiB);      // 2 MiB
  u16* wfcT  = (u16*)(ws + 8 * MiB);      // [FF,D] bf16 = 8 MiB
  u16* wfcaT = (u16*)(ws + 16 * MiB);     // 8 MiB
  u16* woutT = (u16*)(ws + 24 * MiB);     // [D,FF] bf16 = 8 MiB
  float* bcat = (float*)(ws + 32 * MiB);  // [2048] f32
  u16*   xn   = (u16*)(ws + 33 * MiB);    // [M,D] bf16 32 MiB (reused as xn2)
  u16*   zya  = (u16*)(ws + 65 * MiB);    // [M,2048] bf16 64 MiB (reused as Ga)
  float* Abuf = (float*)(ws + 129 * MiB); // [M,D] f32 64 MiB (reused as x1)
  float* Bvbuf= (float*)(ws + 193 * MiB); // [M,D] f32 64 MiB (reused as U)
  u16*   hbf  = (u16*)(ws + 257 * MiB);   // [M,D] bf16 32 MiB
  float* Pbuf = (float*)(ws + 289 * MiB);
  float* Sbuf = (float*)(ws + 290 * MiB);
  float* Hini = (float*)(ws + 291 * MiB); // ends 292 MiB

  float* xout = (float*)d_out;
  float* hout = xout + (size_t)kM * kD;

  const dim3 tb(32, 8);
  wtrans_kernel<<<dim3(kD / 32, kD / 32), tb, 0, stream>>>(w_ln_z, wzyaT, kD, kD);
  wtrans_kernel<<<dim3(kD / 32, kD / 32), tb, 0, stream>>>(w_yact, wzyaT + 1024 * 1024, kD, kD);
  wtrans_kernel<<<dim3(kD / 32, kD / 32), tb, 0, stream>>>(w_dt, wdtT, kD, kD);
  wtrans_kernel<<<dim3(kD / 32, kD / 32), tb, 0, stream>>>(w_y, wyT, kD, kD);
  wtrans_kernel<<<dim3(kFF / 32, kD / 32), tb, 0, stream>>>(w_fc, wfcT, kD, kFF);
  wtrans_kernel<<<dim3(kFF / 32, kD / 32), tb, 0, stream>>>(w_fca, wfcaT, kD, kFF);
  wtrans_kernel<<<dim3(kD / 32, kFF / 32), tb, 0, stream>>>(w_out, woutT, kFF, kD);
  concat_bias<<<8, 256, 0, stream>>>(b_ln_z, b_yact, bcat);

  rmsnorm_kernel<<<kM, 256, 0, stream>>>(x, g_sio, xn);

  // [z | ya] = xn @ [w_ln_z | w_y_act] + [b], bf16 out, N=2048
  gemm_bt<5><<<dim3(2048 / 128, kM / 128), 256, 0, stream>>>(
      xn, wzyaT, bcat, nullptr, 0, nullptr, nullptr, zya, nullptr, kM, 2048, kD);
  // dt GEMM -> A = sigmoid(-dt), Bv = sigmoid(z)*sigmoid(dt)
  gemm_bt<1><<<dim3(kD / 128, kM / 128), 256, 0, stream>>>(
      xn, wdtT, b_dt, zya, 2048, nullptr, Abuf, nullptr, Bvbuf, kM, kD, kD);

  scan_phase1<<<dim3(kD / 256, kNC, kB), 256, 0, stream>>>(Abuf, Bvbuf, Pbuf, Sbuf);
  scan_phase2<<<dim3(kD / 256, kB), 256, 0, stream>>>(Pbuf, Sbuf, hidden, Hini);
  scan_phase3<<<dim3(kD / 256, kNC, kB), 256, 0, stream>>>(Abuf, Bvbuf, Hini, hout, hbf);

  // x1 = (h @ w_y + b_y) * silu(ya) + x   (x1 reuses Abuf; A/Bv dead after scan)
  float* x1 = Abuf;
  gemm_bt<2><<<dim3(kD / 128, kM / 128), 256, 0, stream>>>(
      hbf, wyT, b_y, zya + 1024, 2048, x, x1, nullptr, nullptr, kM, kD, kD);

  rmsnorm_kernel<<<kM, 256, 0, stream>>>(x1, g_ffn, xn);  // xn2 reuses xn

  // FFN in 2 M-chunks of 8192 (Ga reuses zya, U reuses Bvbuf)
  u16* Ga = zya;
  u16* Ubuf = (u16*)Bvbuf;
  for (int ci = 0; ci < 2; ++ci) {
    const int Mc = 8192;
    const u16* xc = xn + (size_t)ci * Mc * kD;
    const float* resc = x1 + (size_t)ci * Mc * kD;
    float* outc = xout + (size_t)ci * Mc * kD;
    gemm_bt<5><<<dim3(kFF / 128, Mc / 128), 256, 0, stream>>>(
        xc, wfcaT, b_fca, nullptr, 0, nullptr, nullptr, Ga, nullptr, Mc, kFF, kD);
    gemm_bt<3><<<dim3(kFF / 128, Mc / 128), 256, 0, stream>>>(
        xc, wfcT, b_fc, Ga, kFF, nullptr, nullptr, Ubuf, nullptr, Mc, kFF, kD);
    gemm_bt<4><<<dim3(kD / 128, Mc / 128), 256, 0, stream>>>(
        Ubuf, woutT, b_out, nullptr, 0, resc, outc, nullptr, nullptr, Mc, kD, kFF);
  }
}

// Round 3
// 821.587 us; speedup vs baseline: 1.6360x; 1.2359x over previous
//
#include <hip/hip_runtime.h>
#include <stdint.h>

using u16 = unsigned short;
typedef __attribute__((ext_vector_type(8))) __bf16 bf16x8;
typedef __attribute__((ext_vector_type(4))) float f32x4;

#define DEV __device__ __forceinline__

static constexpr int kB = 4, kL = 4096, kD = 1024, kFF = 4096;
static constexpr int kM = kB * kL;
static constexpr int kLC = 64, kNC = kL / kLC;
static constexpr float kEPS = 1e-6f;

DEV u16 f2bf(float v) {
  union { float f; uint32_t u; } x; x.f = v;
  uint32_t r = x.u + 0x7FFFu + ((x.u >> 16) & 1u);  // RNE
  return (u16)(r >> 16);
}
DEV float bf2f(u16 u) {
  union { uint32_t u; float f; } x; x.u = (uint32_t)u << 16; return x.f;
}
DEV float sigm(float x) { return 1.0f / (1.0f + __expf(-x)); }

DEV void gload_lds16(const void* g, void* l) {
  __builtin_amdgcn_global_load_lds(
      (const __attribute__((address_space(1))) void*)g,
      (__attribute__((address_space(3))) void*)l, 16, 0, 0);
}

// ---------------- weight transpose + f32->bf16: out[n*K+k] = bf16(in[k*N+n])
__global__ __launch_bounds__(256) void wtrans_kernel(const float* __restrict__ in,
                                                     u16* __restrict__ out,
                                                     int K, int N) {
  __shared__ float t[32][33];
  const int n0 = blockIdx.x * 32, k0 = blockIdx.y * 32;
  const int tx = threadIdx.x, ty = threadIdx.y;
#pragma unroll
  for (int i = 0; i < 4; ++i)
    t[ty + i * 8][tx] = in[(size_t)(k0 + ty + i * 8) * N + (n0 + tx)];
  __syncthreads();
#pragma unroll
  for (int i = 0; i < 4; ++i)
    out[(size_t)(n0 + ty + i * 8) * K + (k0 + tx)] = f2bf(t[tx][ty + i * 8]);
}

__global__ __launch_bounds__(256) void concat_bias(const float* __restrict__ a,
                                                   const float* __restrict__ b,
                                                   float* __restrict__ o) {
  const int i = blockIdx.x * 256 + threadIdx.x;
  if (i < 1024) o[i] = a[i];
  else if (i < 2048) o[i] = b[i - 1024];
}

// ---------------- RMSNorm (f32 in, bf16 out), one block per row, D=1024
__global__ __launch_bounds__(256) void rmsnorm_kernel(const float* __restrict__ x,
                                                      const float* __restrict__ g,
                                                      u16* __restrict__ out) {
  const int row = blockIdx.x;
  const int t = threadIdx.x;
  const float4 v = ((const float4*)(x + (size_t)row * kD))[t];
  float ss = v.x * v.x + v.y * v.y + v.z * v.z + v.w * v.w;
#pragma unroll
  for (int o = 1; o < 64; o <<= 1) ss += __shfl_xor(ss, o, 64);
  __shared__ float red[4];
  if ((t & 63) == 0) red[t >> 6] = ss;
  __syncthreads();
  const float tot = red[0] + red[1] + red[2] + red[3];
  const float sc = rsqrtf(tot * (1.0f / kD) + kEPS);
  const float4 gv = ((const float4*)g)[t];
  const uint32_t lo = (uint32_t)f2bf(v.x * sc * gv.x) | ((uint32_t)f2bf(v.y * sc * gv.y) << 16);
  const uint32_t hi = (uint32_t)f2bf(v.z * sc * gv.z) | ((uint32_t)f2bf(v.w * sc * gv.w) << 16);
  *(uint2*)(out + (size_t)row * kD + t * 4) = make_uint2(lo, hi);
}

// ---------------- 256x256 8-phase GEMM: C = epilogue(A[M,K] @ Bt[N,K]^T + bias)
// 512 thr = 8 waves (2M x 4N), BK=64, 128 KiB LDS (2 dbuf x (A 32K + B 32K)),
// XOR-swizzled LDS (T2) via pre-swizzled global source, counted vmcnt(4) (T4),
// setprio around MFMA clusters (T5), bijective XCD swizzle (T1).
// Staging schedule: A(t) staged at (t-2).Ph4, B(t) at (t-1).Ph1 -> >=3 phases slack.
// MODE 1: Cf = sigmoid(-v); C2 = sigmoid(aux)*sigmoid(v)
// MODE 2: Cf = v*silu(aux) + res
// MODE 3: Cb = bf16(v*silu(aux))
// MODE 4: Cf = v + res
// MODE 5: Cb = bf16(v)
template <int MODE>
__global__ __launch_bounds__(512) void gemm256(
    const u16* __restrict__ A, const u16* __restrict__ Bt,
    const float* __restrict__ bias, const u16* __restrict__ aux, int auxld,
    const float* __restrict__ res, float* __restrict__ Cf,
    u16* __restrict__ Cb, float* __restrict__ C2,
    int M, int N, int K) {
  __shared__ u16 sm[65536];  // 128 KiB
  const int tid = threadIdx.x;
  const int lane = tid & 63;
  const int wave = tid >> 6;
  const int wr = wave >> 2, wc = wave & 3;  // 2 x 4 wave grid

  // bijective XCD swizzle (m204)
  const int gx = gridDim.x;
  const int nwg = gx * gridDim.y;
  const int bid = blockIdx.y * gx + blockIdx.x;
  const int q = nwg >> 3, r = nwg & 7;
  const int xcd = bid & 7, idx0 = bid >> 3;
  const int wg = (xcd < r ? xcd * (q + 1) : r * (q + 1) + (xcd - r) * q) + idx0;
  const int m0 = (wg / gx) * 256, n0 = (wg % gx) * 256;

  const int NK = K >> 6;

  // ---- staging: linear LDS dest (wave-uniform base + lane*16B), inverse-swizzled
  // global source. LDS byte (row*128 + cb) holds global (row, cb ^ ((row&7)<<4)).
  const int l8 = lane >> 3, l7 = lane & 7;
  const int rsub = wave * 8 + l8;            // 0..63 row-sub per load instr
  const int kel = (l7 ^ l8) * 8;             // swizzled k element within 64
  const size_t srcA = (size_t)(m0 + rsub) * K + kel;
  const size_t srcB = (size_t)(n0 + rsub) * K + kel;

  auto stageA = [&](int kt) {
    u16* d = sm + (kt & 1) * 32768 + tid * 8;
    const u16* s = A + srcA + kt * 64;
#pragma unroll
    for (int j = 0; j < 4; ++j) gload_lds16(s + (size_t)j * 64 * K, d + j * 4096);
  };
  auto stageB = [&](int kt) {
    u16* d = sm + (kt & 1) * 32768 + 16384 + tid * 8;
    const u16* s = Bt + srcB + kt * 64;
#pragma unroll
    for (int j = 0; j < 4; ++j) gload_lds16(s + (size_t)j * 64 * K, d + j * 4096);
  };

  // ---- fragment-read offsets (swizzled): row&7 == lane&7 for all frag rows
  const int ra = lane & 15;
  const int kx0 = (((lane >> 4) ^ l7) * 8);        // kk=0
  const int kx1 = ((((lane >> 4) + 4) ^ l7) * 8);  // kk=1

  f32x4 acc[8][4] = {};
  bf16x8 a_[4][2], b_[4][2];

  // prologue: tile0 A+B, tile1 A; wait tile0 landed (tile1-A stays in flight)
  stageA(0); stageB(0); stageA(1);
  asm volatile("s_waitcnt vmcnt(4)");
  asm volatile("s_barrier" ::: "memory");

  for (int h = 0; h < NK; ++h) {
    const u16* Az = sm + (h & 1) * 32768 + (wr * 128 + ra) * 64;
    const u16* Bz = sm + (h & 1) * 32768 + 16384 + (wc * 64 + ra) * 64;

    // ---- Phase 1: read A lo-frags + B lo-frags; stage B(h+1)
#pragma unroll
    for (int mi = 0; mi < 4; ++mi) {
      a_[mi][0] = *(const bf16x8*)(Az + mi * 16 * 64 + kx0);
      a_[mi][1] = *(const bf16x8*)(Az + mi * 16 * 64 + kx1);
    }
#pragma unroll
    for (int ni = 0; ni < 2; ++ni) {
      b_[ni][0] = *(const bf16x8*)(Bz + ni * 16 * 64 + kx0);
      b_[ni][1] = *(const bf16x8*)(Bz + ni * 16 * 64 + kx1);
    }
    if (h + 1 < NK) stageB(h + 1);
    asm volatile("s_barrier" ::: "memory");
    asm volatile("s_waitcnt lgkmcnt(0)");
    __builtin_amdgcn_s_setprio(1);
#pragma unroll
    for (int mi = 0; mi < 4; ++mi)
#pragma unroll
      for (int ni = 0; ni < 2; ++ni)
#pragma unroll
        for (int kk = 0; kk < 2; ++kk)
          acc[mi][ni] = __builtin_amdgcn_mfma_f32_16x16x32_bf16(a_[mi][kk], b_[ni][kk], acc[mi][ni], 0, 0, 0);
    __builtin_amdgcn_s_setprio(0);
    asm volatile("s_barrier" ::: "memory");

    // ---- Phase 2: read B hi-frags
#pragma unroll
    for (int ni = 0; ni < 2; ++ni) {
      b_[2 + ni][0] = *(const bf16x8*)(Bz + (32 + ni * 16) * 64 + kx0);
      b_[2 + ni][1] = *(const bf16x8*)(Bz + (32 + ni * 16) * 64 + kx1);
    }
    asm volatile("s_barrier" ::: "memory");
    asm volatile("s_waitcnt lgkmcnt(0)");
    __builtin_amdgcn_s_setprio(1);
#pragma unroll
    for (int mi = 0; mi < 4; ++mi)
#pragma unroll
      for (int ni = 0; ni < 2; ++ni)
#pragma unroll
        for (int kk = 0; kk < 2; ++kk)
          acc[mi][2 + ni] = __builtin_amdgcn_mfma_f32_16x16x32_bf16(a_[mi][kk], b_[2 + ni][kk], acc[mi][2 + ni], 0, 0, 0);
    __builtin_amdgcn_s_setprio(0);
    asm volatile("s_barrier" ::: "memory");

    // ---- Phase 3: read A hi-frags (overwrite a_)
#pragma unroll
    for (int mi = 0; mi < 4; ++mi) {
      a_[mi][0] = *(const bf16x8*)(Az + (64 + mi * 16) * 64 + kx0);
      a_[mi][1] = *(const bf16x8*)(Az + (64 + mi * 16) * 64 + kx1);
    }
    asm volatile("s_barrier" ::: "memory");
    asm volatile("s_waitcnt lgkmcnt(0)");
    __builtin_amdgcn_s_setprio(1);
#pragma unroll
    for (int mi = 0; mi < 4; ++mi)
#pragma unroll
      for (int ni = 0; ni < 2; ++ni)
#pragma unroll
        for (int kk = 0; kk < 2; ++kk)
          acc[4 + mi][ni] = __builtin_amdgcn_mfma_f32_16x16x32_bf16(a_[mi][kk], b_[ni][kk], acc[4 + mi][ni], 0, 0, 0);
    __builtin_amdgcn_s_setprio(0);
    asm volatile("s_barrier" ::: "memory");

    // ---- Phase 4: stage A(h+2); MFMA hi x hi; counted vmcnt; barrier
    if (h + 2 < NK) stageA(h + 2);
    asm volatile("s_barrier" ::: "memory");
    __builtin_amdgcn_s_setprio(1);
#pragma unroll
    for (int mi = 0; mi < 4; ++mi)
#pragma unroll
      for (int ni = 0; ni < 2; ++ni)
#pragma unroll
        for (int kk = 0; kk < 2; ++kk)
          acc[4 + mi][2 + ni] = __builtin_amdgcn_mfma_f32_16x16x32_bf16(a_[mi][kk], b_[2 + ni][kk], acc[4 + mi][2 + ni], 0, 0, 0);
    __builtin_amdgcn_s_setprio(0);
    if (h + 2 < NK) asm volatile("s_waitcnt vmcnt(4)");  // drain tiles <= h+1; A(h+2) stays in flight
    else            asm volatile("s_waitcnt vmcnt(0)");  // tail: full drain
    asm volatile("s_barrier" ::: "memory");
  }

  // ---- epilogue. C/D layout: col = lane&15, row = (lane>>4)*4 + j
  const int ca = ra;
  const int rq = (lane >> 4) * 4;
#pragma unroll
  for (int mi = 0; mi < 8; ++mi) {
#pragma unroll
    for (int ni = 0; ni < 4; ++ni) {
      const int c = n0 + wc * 64 + ni * 16 + ca;
      const float bz = bias[c];
#pragma unroll
      for (int j = 0; j < 4; ++j) {
        const int rr = m0 + wr * 128 + mi * 16 + rq + j;
        const size_t idx = (size_t)rr * N + c;
        const float v = acc[mi][ni][j] + bz;
        if (MODE == 1) {
          Cf[idx] = sigm(-v);
          C2[idx] = sigm(bf2f(aux[(size_t)rr * auxld + c])) * sigm(v);
        } else if (MODE == 2) {
          const float a = bf2f(aux[(size_t)rr * auxld + c]);
          Cf[idx] = v * (a * sigm(a)) + res[idx];
        } else if (MODE == 3) {
          const float a = bf2f(aux[(size_t)rr * auxld + c]);
          Cb[idx] = f2bf(v * (a * sigm(a)));
        } else if (MODE == 4) {
          Cf[idx] = v + res[idx];
        } else {  // MODE 5
          Cb[idx] = f2bf(v);
        }
      }
    }
  }
}

// ---------------- chunked scan: h[l] = A[l]*h[l-1] + B[l]
__global__ __launch_bounds__(256) void scan_phase1(const float* __restrict__ Aa,
                                                   const float* __restrict__ Bv,
                                                   float* __restrict__ P,
                                                   float* __restrict__ S) {
  const int d = blockIdx.x * 256 + threadIdx.x;
  const int c = blockIdx.y, b = blockIdx.z;
  size_t base = ((size_t)b * kL + (size_t)c * kLC) * kD + d;
  float p = 1.0f, s = 0.0f;
#pragma unroll 4
  for (int l = 0; l < kLC; ++l) {
    const float a = Aa[base];
    const float bv = Bv[base];
    p *= a;
    s = fmaf(a, s, bv);
    base += kD;
  }
  const size_t o = ((size_t)b * kNC + c) * kD + d;
  P[o] = p; S[o] = s;
}

__global__ __launch_bounds__(256) void scan_phase2(const float* __restrict__ P,
                                                   const float* __restrict__ S,
                                                   const float* __restrict__ hidden,
                                                   float* __restrict__ Hini) {
  const int d = blockIdx.x * 256 + threadIdx.x;
  const int b = blockIdx.y;
  float carry = hidden[(size_t)b * kD + d];
  for (int c = 0; c < kNC; ++c) {
    const size_t o = ((size_t)b * kNC + c) * kD + d;
    Hini[o] = carry;
    carry = fmaf(P[o], carry, S[o]);
  }
}

__global__ __launch_bounds__(256) void scan_phase3(const float* __restrict__ Aa,
                                                   const float* __restrict__ Bv,
                                                   const float* __restrict__ Hini,
                                                   float* __restrict__ Hout,
                                                   u16* __restrict__ Hbf) {
  const int d = blockIdx.x * 256 + threadIdx.x;
  const int c = blockIdx.y, b = blockIdx.z;
  float h = Hini[((size_t)b * kNC + c) * kD + d];
  size_t base = ((size_t)b * kL + (size_t)c * kLC) * kD + d;
#pragma unroll 4
  for (int l = 0; l < kLC; ++l) {
    h = fmaf(Aa[base], h, Bv[base]);
    Hout[base] = h;
    Hbf[base] = f2bf(h);
    base += kD;
  }
}

// ---------------- host
extern "C" void kernel_launch(void* const* d_in, const int* in_sizes, int n_in,
                              void* d_out, int out_size, void* d_ws, size_t ws_size,
                              hipStream_t stream) {
  const float* x      = (const float*)d_in[0];
  const float* hidden = (const float*)d_in[1];
  const float* w_ln_z = (const float*)d_in[2];
  const float* b_ln_z = (const float*)d_in[3];
  const float* w_dt   = (const float*)d_in[4];
  const float* b_dt   = (const float*)d_in[5];
  const float* w_y    = (const float*)d_in[6];
  const float* b_y    = (const float*)d_in[7];
  const float* w_yact = (const float*)d_in[8];
  const float* b_yact = (const float*)d_in[9];
  const float* w_fc   = (const float*)d_in[10];
  const float* b_fc   = (const float*)d_in[11];
  const float* w_fca  = (const float*)d_in[12];
  const float* b_fca  = (const float*)d_in[13];
  const float* w_out  = (const float*)d_in[14];
  const float* b_out  = (const float*)d_in[15];
  const float* g_sio  = (const float*)d_in[16];
  const float* g_ffn  = (const float*)d_in[17];

  char* ws = (char*)d_ws;
  const size_t MiB = 1ull << 20;
  u16* wzyaT = (u16*)(ws + 0 * MiB);      // [2048,1024] bf16 (ln_z | y_act)
  u16* wdtT  = (u16*)(ws + 4 * MiB);
  u16* wyT   = (u16*)(ws + 6 * MiB);
  u16* wfcT  = (u16*)(ws + 8 * MiB);      // [FF,D]
  u16* wfcaT = (u16*)(ws + 16 * MiB);
  u16* woutT = (u16*)(ws + 24 * MiB);     // [D,FF]
  float* bcat = (float*)(ws + 32 * MiB);
  u16*   xn   = (u16*)(ws + 33 * MiB);    // [M,D] bf16 32 MiB (reused as xn2)
  u16*   zya  = (u16*)(ws + 65 * MiB);    // [M,2048] bf16 64 MiB (reused as Ga chunk)
  float* Abuf = (float*)(ws + 129 * MiB); // [M,D] f32 64 MiB (reused as x1)
  float* Bvbuf= (float*)(ws + 193 * MiB); // [M,D] f32 (dead after scan)
  u16*   hbf  = (u16*)(ws + 257 * MiB);   // [M,D] bf16 (dead after y-GEMM)
  float* Pbuf = (float*)(ws + 289 * MiB);
  float* Sbuf = (float*)(ws + 290 * MiB);
  float* Hini = (float*)(ws + 291 * MiB);
  u16*   Ubuf = (u16*)(ws + 193 * MiB);   // [M,FF] bf16 128 MiB, overlays dead Bv/hbf/scan; ends 321 MiB

  float* xout = (float*)d_out;
  float* hout = xout + (size_t)kM * kD;

  const dim3 tb(32, 8);
  wtrans_kernel<<<dim3(kD / 32, kD / 32), tb, 0, stream>>>(w_ln_z, wzyaT, kD, kD);
  wtrans_kernel<<<dim3(kD / 32, kD / 32), tb, 0, stream>>>(w_yact, wzyaT + 1024 * 1024, kD, kD);
  wtrans_kernel<<<dim3(kD / 32, kD / 32), tb, 0, stream>>>(w_dt, wdtT, kD, kD);
  wtrans_kernel<<<dim3(kD / 32, kD / 32), tb, 0, stream>>>(w_y, wyT, kD, kD);
  wtrans_kernel<<<dim3(kFF / 32, kD / 32), tb, 0, stream>>>(w_fc, wfcT, kD, kFF);
  wtrans_kernel<<<dim3(kFF / 32, kD / 32), tb, 0, stream>>>(w_fca, wfcaT, kD, kFF);
  wtrans_kernel<<<dim3(kD / 32, kFF / 32), tb, 0, stream>>>(w_out, woutT, kFF, kD);
  concat_bias<<<8, 256, 0, stream>>>(b_ln_z, b_yact, bcat);

  rmsnorm_kernel<<<kM, 256, 0, stream>>>(x, g_sio, xn);

  // [z | ya] = xn @ [w_ln_z | w_y_act] + [b], bf16 out
  gemm256<5><<<dim3(2048 / 256, kM / 256), 512, 0, stream>>>(
      xn, wzyaT, bcat, nullptr, 0, nullptr, nullptr, zya, nullptr, kM, 2048, kD);
  // dt GEMM -> A = sigmoid(-dt), Bv = sigmoid(z)*sigmoid(dt)
  gemm256<1><<<dim3(kD / 256, kM / 256), 512, 0, stream>>>(
      xn, wdtT, b_dt, zya, 2048, nullptr, Abuf, nullptr, Bvbuf, kM, kD, kD);

  scan_phase1<<<dim3(kD / 256, kNC, kB), 256, 0, stream>>>(Abuf, Bvbuf, Pbuf, Sbuf);
  scan_phase2<<<dim3(kD / 256, kB), 256, 0, stream>>>(Pbuf, Sbuf, hidden, Hini);
  scan_phase3<<<dim3(kD / 256, kNC, kB), 256, 0, stream>>>(Abuf, Bvbuf, Hini, hout, hbf);

  // x1 = (h @ w_y + b_y) * silu(ya) + x   (x1 reuses Abuf)
  float* x1 = Abuf;
  gemm256<2><<<dim3(kD / 256, kM / 256), 512, 0, stream>>>(
      hbf, wyT, b_y, zya + 1024, 2048, x, x1, nullptr, nullptr, kM, kD, kD);

  rmsnorm_kernel<<<kM, 256, 0, stream>>>(x1, g_ffn, xn);

  // FFN: gate GEMMs in 2 M-chunks (Ga reuses zya); U is full-M
  for (int ci = 0; ci < 2; ++ci) {
    const int Mc = 8192;
    const u16* xc = xn + (size_t)ci * Mc * kD;
    u16* Ga = zya;
    gemm256<5><<<dim3(kFF / 256, Mc / 256), 512, 0, stream>>>(
        xc, wfcaT, b_fca, nullptr, 0, nullptr, nullptr, Ga, nullptr, Mc, kFF, kD);
    gemm256<3><<<dim3(kFF / 256, Mc / 256), 512, 0, stream>>>(
        xc, wfcT, b_fc, Ga, kFF, nullptr, nullptr, Ubuf + (size_t)ci * Mc * kFF, nullptr, Mc, kFF, kD);
  }
  // xout = U @ w_out + b_out + x1  (full M, K=4096, 256 blocks = 1/CU)
  gemm256<4><<<dim3(kD / 256, kM / 256), 512, 0, stream>>>(
      Ubuf, woutT, b_out, nullptr, 0, x1, xout, nullptr, nullptr, kM, kD, kFF);
}

// Round 5
// 767.513 us; speedup vs baseline: 1.7512x; 1.0705x over previous
//
#include <hip/hip_runtime.h>
#include <stdint.h>

using u16 = unsigned short;
typedef __attribute__((ext_vector_type(8))) __bf16 bf16x8;
typedef __attribute__((ext_vector_type(4))) float f32x4;

#define DEV __device__ __forceinline__

static constexpr int kB = 4, kL = 4096, kD = 1024, kFF = 4096;
static constexpr int kM = kB * kL;
static constexpr int kLC = 256, kNC = kL / kLC;
static constexpr float kEPS = 1e-6f;

DEV u16 f2bf(float v) {
  union { float f; uint32_t u; } x; x.f = v;
  uint32_t r = x.u + 0x7FFFu + ((x.u >> 16) & 1u);  // RNE
  return (u16)(r >> 16);
}
DEV float bf2f(u16 u) {
  union { uint32_t u; float f; } x; x.u = (uint32_t)u << 16; return x.f;
}
DEV float sigm(float x) { return 1.0f / (1.0f + __expf(-x)); }

DEV void gload_lds16(const void* g, void* l) {
  __builtin_amdgcn_global_load_lds(
      (const __attribute__((address_space(1))) void*)g,
      (__attribute__((address_space(3))) void*)l, 16, 0, 0);
}

// ---------------- weight transpose + f32->bf16: out[n*K+k] = bf16(in[k*N+n])
__global__ __launch_bounds__(256) void wtrans_kernel(const float* __restrict__ in,
                                                     u16* __restrict__ out,
                                                     int K, int N) {
  __shared__ float t[32][33];
  const int n0 = blockIdx.x * 32, k0 = blockIdx.y * 32;
  const int tx = threadIdx.x, ty = threadIdx.y;
#pragma unroll
  for (int i = 0; i < 4; ++i)
    t[ty + i * 8][tx] = in[(size_t)(k0 + ty + i * 8) * N + (n0 + tx)];
  __syncthreads();
#pragma unroll
  for (int i = 0; i < 4; ++i)
    out[(size_t)(n0 + ty + i * 8) * K + (k0 + tx)] = f2bf(t[tx][ty + i * 8]);
}

// paired transpose: out rows interleave a and b in 32-col groups.
// out row n (of 2*Ncols): g=n>>6, r=n&63; src = (r<32? a : b), col = g*32 + (r&31).
__global__ __launch_bounds__(256) void wtrans_pair(const float* __restrict__ a,
                                                   const float* __restrict__ b,
                                                   u16* __restrict__ out,
                                                   int K, int Ncols) {
  __shared__ float t[32][33];
  const int n0 = blockIdx.x * 32, k0 = blockIdx.y * 32;
  const int sel = (n0 >> 5) & 1;
  const int c0 = (n0 >> 6) * 32;
  const float* __restrict__ src = sel ? b : a;
  const int tx = threadIdx.x, ty = threadIdx.y;
#pragma unroll
  for (int i = 0; i < 4; ++i)
    t[ty + i * 8][tx] = src[(size_t)(k0 + ty + i * 8) * Ncols + (c0 + tx)];
  __syncthreads();
#pragma unroll
  for (int i = 0; i < 4; ++i)
    out[(size_t)(n0 + ty + i * 8) * K + (k0 + tx)] = f2bf(t[tx][ty + i * 8]);
}

// ---------------- RMSNorm (f32 in, bf16 out), one block per row, D=1024
__global__ __launch_bounds__(256) void rmsnorm_kernel(const float* __restrict__ x,
                                                      const float* __restrict__ g,
                                                      u16* __restrict__ out) {
  const int row = blockIdx.x;
  const int t = threadIdx.x;
  const float4 v = ((const float4*)(x + (size_t)row * kD))[t];
  float ss = v.x * v.x + v.y * v.y + v.z * v.z + v.w * v.w;
#pragma unroll
  for (int o = 1; o < 64; o <<= 1) ss += __shfl_xor(ss, o, 64);
  __shared__ float red[4];
  if ((t & 63) == 0) red[t >> 6] = ss;
  __syncthreads();
  const float tot = red[0] + red[1] + red[2] + red[3];
  const float sc = rsqrtf(tot * (1.0f / kD) + kEPS);
  const float4 gv = ((const float4*)g)[t];
  const uint32_t lo = (uint32_t)f2bf(v.x * sc * gv.x) | ((uint32_t)f2bf(v.y * sc * gv.y) << 16);
  const uint32_t hi = (uint32_t)f2bf(v.z * sc * gv.z) | ((uint32_t)f2bf(v.w * sc * gv.w) << 16);
  *(uint2*)(out + (size_t)row * kD + t * 4) = make_uint2(lo, hi);
}

// ---------------- 256x256 lockstep 4-phase GEMM (round-3 schedule + spread staging)
// 512 thr = 8 waves (2M x 4N), BK=64, 128 KiB LDS dbuf, T2 XOR swizzle via
// pre-swizzled global source, T1 XCD swizzle, T5 setprio.
// Staging ledger (half = 2 gloads; halves: 0=A-lo,1=A-hi,2=B-lo,3=B-hi):
//   ph1(h): stage(h+1,#1)->buf q   [buf-q readers (tile h-1) certified by iter-(h-1) end-ph3 barrier]
//   ph2(h): stage(h+1,#2)->buf q
//   ph3(h): stage(h+1,#3)->buf q
//   ph4(h): stage(h+2,#0)->buf p   [buf-p readers (tile h) certified by this iter's end-ph3 barrier]
//           then vmcnt(2) (keeps only (h+2,#0) in flight; tile h+1 fully landed); vmcnt(0) at tail.
// Reads feed the SAME phase's MFMA after barrier+lgkmcnt(0) -> lockstep, no cross-phase reg hazards.
// MODE 2: Cf = v*silu(aux) + res        (y + residual; aux bf16)
// MODE 4: Cf = v + res                  (final out)
// MODE 5: Cb = bf16(v)                  (raw bf16)
// MODE 6: pair FFN: v1=fca(gate), v2=fc -> Cb = bf16(v2*silu(v1)), Nout=N/2
// MODE 7: pair coeffs: v1=z, v2=dt -> Cf = sigm(-v2), C2 = sigm(v1)*sigm(v2), Nout=N/2
template <int MODE>
__global__ __launch_bounds__(512) void gemm256(
    const u16* __restrict__ A, const u16* __restrict__ Bt,
    const float* __restrict__ bias, const float* __restrict__ bias2,
    const u16* __restrict__ aux, int auxld,
    const float* __restrict__ res, float* __restrict__ Cf,
    u16* __restrict__ Cb, float* __restrict__ C2,
    int M, int N, int K) {
  __shared__ u16 sm[65536];  // 128 KiB
  const int tid = threadIdx.x;
  const int lane = tid & 63;
  const int wave = tid >> 6;
  const int wr = wave >> 2, wc = wave & 3;  // 2 x 4 wave grid

  // bijective XCD swizzle (m204)
  const int gx = gridDim.x;
  const int nwg = gx * gridDim.y;
  const int bid = blockIdx.y * gx + blockIdx.x;
  const int q = nwg >> 3, r = nwg & 7;
  const int xcd = bid & 7, idx0 = bid >> 3;
  const int wg = (xcd < r ? xcd * (q + 1) : r * (q + 1) + (xcd - r) * q) + idx0;
  const int m0 = (wg / gx) * 256, n0 = (wg % gx) * 256;

  const int NK = K >> 6;

  // staging: linear LDS dest, inverse-swizzled global source.
  const int l8 = lane >> 3, l7 = lane & 7;
  const int rsub = wave * 8 + l8;
  const int kel = (l7 ^ l8) * 8;
  const size_t srcA = (size_t)(m0 + rsub) * K + kel;
  const size_t srcB = (size_t)(n0 + rsub) * K + kel;

  // half: 0 = A rows 0-127, 1 = A rows 128-255, 2 = B rows 0-127, 3 = B rows 128-255
  auto stage_half = [&](int kt, int half) {
    const int bsel = (kt & 1) * 32768;
    if (half < 2) {
      u16* d = sm + bsel + tid * 8 + half * 8192;
      const u16* s = A + srcA + (size_t)kt * 64 + (size_t)(half * 2) * 64 * K;
      gload_lds16(s, d);
      gload_lds16(s + (size_t)64 * K, d + 4096);
    } else {
      const int hh = half - 2;
      u16* d = sm + bsel + 16384 + tid * 8 + hh * 8192;
      const u16* s = Bt + srcB + (size_t)kt * 64 + (size_t)(hh * 2) * 64 * K;
      gload_lds16(s, d);
      gload_lds16(s + (size_t)64 * K, d + 4096);
    }
  };

  // fragment-read offsets (swizzled)
  const int ra = lane & 15;
  const int kx0 = ((lane >> 4) ^ l7) * 8;
  const int kx1 = (((lane >> 4) + 4) ^ l7) * 8;

  f32x4 acc[8][4] = {};
  bf16x8 al[4][2], ah[4][2], bl[2][2], bh[2][2];

  // prologue: tile0 all halves + tile1 half0; drain tile0, keep (1,#0) in flight
  stage_half(0, 0); stage_half(0, 1); stage_half(0, 2); stage_half(0, 3);
  stage_half(1, 0);
  asm volatile("s_waitcnt vmcnt(2)");
  asm volatile("s_barrier" ::: "memory");

  for (int h = 0; h < NK; ++h) {
    const u16* Az = sm + (h & 1) * 32768 + (wr * 128 + ra) * 64;
    const u16* Bz = sm + (h & 1) * 32768 + 16384 + (wc * 64 + ra) * 64;

    // ---- Phase 1: read A-lo + B-lo; stage (h+1,#1)
#pragma unroll
    for (int mi = 0; mi < 4; ++mi) {
      al[mi][0] = *(const bf16x8*)(Az + mi * 16 * 64 + kx0);
      al[mi][1] = *(const bf16x8*)(Az + mi * 16 * 64 + kx1);
    }
#pragma unroll
    for (int ni = 0; ni < 2; ++ni) {
      bl[ni][0] = *(const bf16x8*)(Bz + ni * 16 * 64 + kx0);
      bl[ni][1] = *(const bf16x8*)(Bz + ni * 16 * 64 + kx1);
    }
    if (h + 1 < NK) stage_half(h + 1, 1);
    asm volatile("s_barrier" ::: "memory");
    asm volatile("s_waitcnt lgkmcnt(0)");
    __builtin_amdgcn_s_setprio(1);
#pragma unroll
    for (int mi = 0; mi < 4; ++mi)
#pragma unroll
      for (int ni = 0; ni < 2; ++ni)
#pragma unroll
        for (int kk = 0; kk < 2; ++kk)
          acc[mi][ni] = __builtin_amdgcn_mfma_f32_16x16x32_bf16(al[mi][kk], bl[ni][kk], acc[mi][ni], 0, 0, 0);
    __builtin_amdgcn_s_setprio(0);
    asm volatile("s_barrier" ::: "memory");

    // ---- Phase 2: read B-hi; stage (h+1,#2)
#pragma unroll
    for (int ni = 0; ni < 2; ++ni) {
      bh[ni][0] = *(const bf16x8*)(Bz + (32 + ni * 16) * 64 + kx0);
      bh[ni][1] = *(const bf16x8*)(Bz + (32 + ni * 16) * 64 + kx1);
    }
    if (h + 1 < NK) stage_half(h + 1, 2);
    asm volatile("s_barrier" ::: "memory");
    asm volatile("s_waitcnt lgkmcnt(0)");
    __builtin_amdgcn_s_setprio(1);
#pragma unroll
    for (int mi = 0; mi < 4; ++mi)
#pragma unroll
      for (int ni = 0; ni < 2; ++ni)
#pragma unroll
        for (int kk = 0; kk < 2; ++kk)
          acc[mi][2 + ni] = __builtin_amdgcn_mfma_f32_16x16x32_bf16(al[mi][kk], bh[ni][kk], acc[mi][2 + ni], 0, 0, 0);
    __builtin_amdgcn_s_setprio(0);
    asm volatile("s_barrier" ::: "memory");

    // ---- Phase 3: read A-hi; stage (h+1,#3)
#pragma unroll
    for (int mi = 0; mi < 4; ++mi) {
      ah[mi][0] = *(const bf16x8*)(Az + (64 + mi * 16) * 64 + kx0);
      ah[mi][1] = *(const bf16x8*)(Az + (64 + mi * 16) * 64 + kx1);
    }
    if (h + 1 < NK) stage_half(h + 1, 3);
    asm volatile("s_barrier" ::: "memory");
    asm volatile("s_waitcnt lgkmcnt(0)");
    __builtin_amdgcn_s_setprio(1);
#pragma unroll
    for (int mi = 0; mi < 4; ++mi)
#pragma unroll
      for (int ni = 0; ni < 2; ++ni)
#pragma unroll
        for (int kk = 0; kk < 2; ++kk)
          acc[4 + mi][ni] = __builtin_amdgcn_mfma_f32_16x16x32_bf16(ah[mi][kk], bl[ni][kk], acc[4 + mi][ni], 0, 0, 0);
    __builtin_amdgcn_s_setprio(0);
    asm volatile("s_barrier" ::: "memory");

    // ---- Phase 4: stage (h+2,#0); MFMA hi x hi; counted vmcnt; barrier
    if (h + 2 < NK) stage_half(h + 2, 0);
    asm volatile("s_barrier" ::: "memory");
    __builtin_amdgcn_s_setprio(1);
#pragma unroll
    for (int mi = 0; mi < 4; ++mi)
#pragma unroll
      for (int ni = 0; ni < 2; ++ni)
#pragma unroll
        for (int kk = 0; kk < 2; ++kk)
          acc[4 + mi][2 + ni] = __builtin_amdgcn_mfma_f32_16x16x32_bf16(ah[mi][kk], bh[ni][kk], acc[4 + mi][2 + ni], 0, 0, 0);
    __builtin_amdgcn_s_setprio(0);
    if (h + 2 < NK) asm volatile("s_waitcnt vmcnt(2)");  // tile h+1 landed; (h+2,#0) in flight
    else            asm volatile("s_waitcnt vmcnt(0)");  // tail: full drain
    asm volatile("s_barrier" ::: "memory");
  }

  // ---- epilogue. C/D layout: col = lane&15, row = (lane>>4)*4 + j
  const int ca = ra;
  const int rq = (lane >> 4) * 4;
  if (MODE == 6 || MODE == 7) {
    const int Nout = N >> 1;
#pragma unroll
    for (int mi = 0; mi < 8; ++mi) {
#pragma unroll
      for (int ni = 0; ni < 2; ++ni) {
        const int cout = (n0 >> 1) + wc * 32 + ni * 16 + ca;
        const float b1 = bias[cout], b2 = bias2[cout];
#pragma unroll
        for (int j = 0; j < 4; ++j) {
          const int rr = m0 + wr * 128 + mi * 16 + rq + j;
          const size_t idx = (size_t)rr * Nout + cout;
          const float v1 = acc[mi][ni][j] + b1;
          const float v2 = acc[mi][2 + ni][j] + b2;
          if (MODE == 7) {
            Cf[idx] = sigm(-v2);              // decay A
            C2[idx] = sigm(v1) * sigm(v2);    // input B
          } else {
            Cb[idx] = f2bf(v2 * (v1 * sigm(v1)));  // fc * silu(fca)
          }
        }
      }
    }
  } else {
#pragma unroll
    for (int mi = 0; mi < 8; ++mi) {
#pragma unroll
      for (int ni = 0; ni < 4; ++ni) {
        const int c = n0 + wc * 64 + ni * 16 + ca;
        const float bz = bias[c];
#pragma unroll
        for (int j = 0; j < 4; ++j) {
          const int rr = m0 + wr * 128 + mi * 16 + rq + j;
          const size_t idx = (size_t)rr * N + c;
          const float v = acc[mi][ni][j] + bz;
          if (MODE == 2) {
            const float a = bf2f(aux[(size_t)rr * auxld + c]);
            Cf[idx] = v * (a * sigm(a)) + res[idx];
          } else if (MODE == 4) {
            Cf[idx] = v + res[idx];
          } else {  // MODE 5
            Cb[idx] = f2bf(v);
          }
        }
      }
    }
  }
}

// ---------------- chunked scan: h[l] = A[l]*h[l-1] + B[l]
__global__ __launch_bounds__(256) void scan_phase1(const float* __restrict__ Aa,
                                                   const float* __restrict__ Bv,
                                                   float* __restrict__ P,
                                                   float* __restrict__ S) {
  const int d = blockIdx.x * 256 + threadIdx.x;
  const int c = blockIdx.y, b = blockIdx.z;
  size_t base = ((size_t)b * kL + (size_t)c * kLC) * kD + d;
  float p = 1.0f, s = 0.0f;
#pragma unroll 4
  for (int l = 0; l < kLC; ++l) {
    const float a = Aa[base];
    const float bv = Bv[base];
    p *= a;
    s = fmaf(a, s, bv);
    base += kD;
  }
  const size_t o = ((size_t)b * kNC + c) * kD + d;
  P[o] = p; S[o] = s;
}

__global__ __launch_bounds__(256) void scan_phase2(const float* __restrict__ P,
                                                   const float* __restrict__ S,
                                                   const float* __restrict__ hidden,
                                                   float* __restrict__ Hini) {
  const int d = blockIdx.x * 256 + threadIdx.x;
  const int b = blockIdx.y;
  float carry = hidden[(size_t)b * kD + d];
  for (int c = 0; c < kNC; ++c) {
    const size_t o = ((size_t)b * kNC + c) * kD + d;
    Hini[o] = carry;
    carry = fmaf(P[o], carry, S[o]);
  }
}

__global__ __launch_bounds__(256) void scan_phase3(const float* __restrict__ Aa,
                                                   const float* __restrict__ Bv,
                                                   const float* __restrict__ Hini,
                                                   float* __restrict__ Hout,
                                                   u16* __restrict__ Hbf) {
  const int d = blockIdx.x * 256 + threadIdx.x;
  const int c = blockIdx.y, b = blockIdx.z;
  float h = Hini[((size_t)b * kNC + c) * kD + d];
  size_t base = ((size_t)b * kL + (size_t)c * kLC) * kD + d;
#pragma unroll 4
  for (int l = 0; l < kLC; ++l) {
    h = fmaf(Aa[base], h, Bv[base]);
    Hout[base] = h;
    Hbf[base] = f2bf(h);
    base += kD;
  }
}

// ---------------- host
extern "C" void kernel_launch(void* const* d_in, const int* in_sizes, int n_in,
                              void* d_out, int out_size, void* d_ws, size_t ws_size,
                              hipStream_t stream) {
  const float* x      = (const float*)d_in[0];
  const float* hidden = (const float*)d_in[1];
  const float* w_ln_z = (const float*)d_in[2];
  const float* b_ln_z = (const float*)d_in[3];
  const float* w_dt   = (const float*)d_in[4];
  const float* b_dt   = (const float*)d_in[5];
  const float* w_y    = (const float*)d_in[6];
  const float* b_y    = (const float*)d_in[7];
  const float* w_yact = (const float*)d_in[8];
  const float* b_yact = (const float*)d_in[9];
  const float* w_fc   = (const float*)d_in[10];
  const float* b_fc   = (const float*)d_in[11];
  const float* w_fca  = (const float*)d_in[12];
  const float* b_fca  = (const float*)d_in[13];
  const float* w_out  = (const float*)d_in[14];
  const float* b_out  = (const float*)d_in[15];
  const float* g_sio  = (const float*)d_in[16];
  const float* g_ffn  = (const float*)d_in[17];

  char* ws = (char*)d_ws;
  const size_t MiB = 1ull << 20;
  u16* wzdT  = (u16*)(ws + 0 * MiB);      // [2048,1024] paired z|dt, 4 MiB
  u16* wyaT  = (u16*)(ws + 4 * MiB);      // 2 MiB
  u16* wyT   = (u16*)(ws + 6 * MiB);      // 2 MiB
  u16* wfgT  = (u16*)(ws + 8 * MiB);      // [8192,1024] paired fca|fc, 16 MiB
  u16* woutT = (u16*)(ws + 24 * MiB);     // [1024,4096] 8 MiB
  u16*   xn    = (u16*)(ws + 33 * MiB);   // [M,D] bf16 32 MiB (reused as xn2)
  u16*   yabuf = (u16*)(ws + 65 * MiB);   // [M,D] bf16 32 MiB
  float* Abuf  = (float*)(ws + 97 * MiB); // [M,D] f32 64 MiB (reused as x1)
  float* Bvbuf = (float*)(ws + 161 * MiB);// [M,D] f32 64 MiB (dead after scan)
  u16*   hbf   = (u16*)(ws + 225 * MiB);  // [M,D] bf16 32 MiB (dead after y-GEMM)
  u16*   Ubuf  = (u16*)(ws + 161 * MiB);  // [M,FF] bf16 128 MiB, overlays dead Bv/hbf; ends 289
  float* Pbuf  = (float*)(ws + 289 * MiB);
  float* Sbuf  = (float*)(ws + 290 * MiB);
  float* Hini  = (float*)(ws + 291 * MiB);// ends 292 MiB

  float* xout = (float*)d_out;
  float* hout = xout + (size_t)kM * kD;
  float* x1 = Abuf;

  const dim3 tb(32, 8);
  wtrans_pair<<<dim3(2048 / 32, kD / 32), tb, 0, stream>>>(w_ln_z, w_dt, wzdT, kD, kD);
  wtrans_pair<<<dim3(8192 / 32, kD / 32), tb, 0, stream>>>(w_fca, w_fc, wfgT, kD, kFF);
  wtrans_kernel<<<dim3(kD / 32, kD / 32), tb, 0, stream>>>(w_yact, wyaT, kD, kD);
  wtrans_kernel<<<dim3(kD / 32, kD / 32), tb, 0, stream>>>(w_y, wyT, kD, kD);
  wtrans_kernel<<<dim3(kD / 32, kFF / 32), tb, 0, stream>>>(w_out, woutT, kFF, kD);

  rmsnorm_kernel<<<kM, 256, 0, stream>>>(x, g_sio, xn);

  // paired z|dt GEMM -> A = sigm(-dt), Bv = sigm(z)*sigm(dt)   (no z materialized)
  gemm256<7><<<dim3(2048 / 256, kM / 256), 512, 0, stream>>>(
      xn, wzdT, b_ln_z, b_dt, nullptr, 0, nullptr, Abuf, nullptr, Bvbuf, kM, 2048, kD);
  // ya = xn @ w_y_act + b (bf16)
  gemm256<5><<<dim3(kD / 256, kM / 256), 512, 0, stream>>>(
      xn, wyaT, b_yact, nullptr, nullptr, 0, nullptr, nullptr, yabuf, nullptr, kM, kD, kD);

  scan_phase1<<<dim3(kD / 256, kNC, kB), 256, 0, stream>>>(Abuf, Bvbuf, Pbuf, Sbuf);
  scan_phase2<<<dim3(kD / 256, kB), 256, 0, stream>>>(Pbuf, Sbuf, hidden, Hini);
  scan_phase3<<<dim3(kD / 256, kNC, kB), 256, 0, stream>>>(Abuf, Bvbuf, Hini, hout, hbf);

  // x1 = (h @ w_y + b_y) * silu(ya) + x   (x1 reuses Abuf; A/Bv dead after scan)
  gemm256<2><<<dim3(kD / 256, kM / 256), 512, 0, stream>>>(
      hbf, wyT, b_y, nullptr, yabuf, kD, x, x1, nullptr, nullptr, kM, kD, kD);

  rmsnorm_kernel<<<kM, 256, 0, stream>>>(x1, g_ffn, xn);

  // paired FFN up+gate: U = fc * silu(fca), full M, in-register gating
  gemm256<6><<<dim3(8192 / 256, kM / 256), 512, 0, stream>>>(
      xn, wfgT, b_fca, b_fc, nullptr, 0, nullptr, nullptr, Ubuf, nullptr, kM, 8192, kD);

  // xout = U @ w_out + b_out + x1  (K=4096)
  gemm256<4><<<dim3(kD / 256, kM / 256), 512, 0, stream>>>(
      Ubuf, woutT, b_out, nullptr, nullptr, 0, x1, xout, nullptr, nullptr, kM, kD, kFF);
}